// Round 8
// baseline (491.455 us; speedup 1.0000x reference)
//
#include <hip/hip_runtime.h>

#define N_NODES 100000
#define N_EDGES 3200000
#define IN_DIM 256
#define HIDDEN 128
#define OUT_DIM 64

#define NBUCK 782        // ceil(100000 / 128) buckets of 128 dst rows
#define CHUNK 3072       // edges per partition block
#define NPT (CHUNK / 256)
#define NPB ((N_EDGES + CHUNK - 1) / CHUNK)   // 1042 pass-1 chunks
#define BCAP 6144        // max edges per bucket for LDS sort (mean 4096, sd 64)
#define CURSTRIDE 32     // pad cursors to one per 128B line
#define NCG 13           // coarse groups: dst>>13
#define CGBITS 13
#define MAXCH 92         // max pass-2 chunks per coarse group

typedef unsigned int uint32;
typedef unsigned short ushort16;

typedef short short8 __attribute__((ext_vector_type(8)));   // 8 bf16 (4 VGPRs)
typedef float f32x4 __attribute__((ext_vector_type(4)));    // MFMA acc

// round-to-nearest-even f32 -> bf16
__device__ __forceinline__ ushort16 f2bf(float f) {
    uint32 u = __float_as_uint(f);
    u += 0x7fffu + ((u >> 16) & 1u);
    return (ushort16)(u >> 16);
}

// split f32 into bf16 hi + bf16 lo, f ~= hi + lo (error ~2^-16 rel)
__device__ __forceinline__ void splitbf(float f, unsigned short& hi, unsigned short& lo) {
    uint32 u = __float_as_uint(f);
    uint32 r = u + 0x7fffu + ((u >> 16) & 1u);
    hi = (unsigned short)(r >> 16);
    float hf = __uint_as_float((r >> 16) << 16);
    float res = f - hf;                    // exact (Sterbenz: same binade)
    uint32 v = __float_as_uint(res);
    lo = (unsigned short)((v + 0x7fffu + ((v >> 16) & 1u)) >> 16);
}

// ---------------- chunk-aligned histogram: fine-bucket counts + per-chunk group counts ----

__global__ __launch_bounds__(256)
void hist_bucket(const int* __restrict__ edst, int* __restrict__ bcnt,
                 int* __restrict__ chunk_hist, int E) {
    __shared__ int h[NBUCK];
    int tid = threadIdx.x;
    long base = (long)blockIdx.x * CHUNK;
    int cnt = (int)min((long)CHUNK, (long)E - base);
    for (int b = tid; b < NBUCK; b += 256) h[b] = 0;
    __syncthreads();
    for (int j = tid; j < cnt; j += 256)
        atomicAdd(&h[edst[base + j] >> 7], 1);
    __syncthreads();
    for (int b = tid; b < NBUCK; b += 256) {
        int c = h[b];
        if (c) atomicAdd(&bcnt[b], c);
    }
    // coarse-group counts for this chunk = sum of its fine buckets (no extra atomics)
    if (tid < NCG) {
        int b0 = tid * 64, b1 = min(b0 + 64, NBUCK);
        int s = 0;
        for (int b = b0; b < b1; b++) s += h[b];
        chunk_hist[blockIdx.x * 16 + tid] = s;
    }
}

// ---------------- bucket exclusive scan (one block) ----------------

__global__ __launch_bounds__(256)
void bucket_scan(const int* __restrict__ bcnt, int* __restrict__ bptr,
                 int* __restrict__ cursor, int* __restrict__ row_ptr, int E) {
    __shared__ int st[256];
    int tid = threadIdx.x;
    int v4[4];
    int s0 = 0;
#pragma unroll
    for (int k = 0; k < 4; k++) {
        int b = tid * 4 + k;
        v4[k] = (b < NBUCK) ? bcnt[b] : 0;
        s0 += v4[k];
    }
    st[tid] = s0;
    __syncthreads();
    for (int off = 1; off < 256; off <<= 1) {
        int t = (tid >= off) ? st[tid - off] : 0;
        __syncthreads();
        st[tid] += t;
        __syncthreads();
    }
    int run = st[tid] - s0;
#pragma unroll
    for (int k = 0; k < 4; k++) {
        int b = tid * 4 + k;
        if (b < NBUCK) { bptr[b] = run; cursor[b * CURSTRIDE] = run; }
        run += v4[k];
    }
    if (tid == 255) bptr[NBUCK] = run;
    if (tid == 0) row_ptr[N_NODES] = E;
}

// ---------------- scan over chunks per coarse group -> deterministic chunk bases ----------
// Block g computes chunk_base[c][g] = bptr[64g] + sum_{c'<c} chunk_hist[c'][g].

__global__ __launch_bounds__(256)
void scan_chunks(const int* __restrict__ chunk_hist, const int* __restrict__ bptr,
                 int* __restrict__ chunk_base) {
    __shared__ int st[256];
    int g = blockIdx.x;
    int tid = threadIdx.x;
    int carry = bptr[min(64 * g, NBUCK)];
    for (int t0 = 0; t0 < NPB; t0 += 256) {
        int c = t0 + tid;
        int v = (c < NPB) ? chunk_hist[c * 16 + g] : 0;
        st[tid] = v;
        __syncthreads();
        int sum = v;
        for (int off = 1; off < 256; off <<= 1) {
            int t = (tid >= off) ? st[tid - off] : 0;
            __syncthreads();
            sum += t;
            st[tid] = sum;
            __syncthreads();
        }
        if (c < NPB) chunk_base[c * 16 + g] = carry + sum - v;
        int tot = st[255];
        __syncthreads();
        carry += tot;
    }
}

// ---------------- per-bucket counting sort -> row-sorted CSR (in place) ----------------

__global__ __launch_bounds__(512)
void bucket_to_csr(const int* __restrict__ bptr, int2* __restrict__ part,
                   int* __restrict__ row_ptr) {
    __shared__ int2 se[BCAP];
    __shared__ int rcnt[128];
    __shared__ int rcur[128];
    int tid = threadIdx.x;
    int b = blockIdx.x;
    int s = bptr[b], e = bptr[b + 1];
    int cnt = min(e - s, BCAP);

    if (tid < 128) rcnt[tid] = 0;
    __syncthreads();
    for (int j = tid; j < cnt; j += 512) {
        int2 p = part[s + j];
        se[j] = p;
        atomicAdd(&rcnt[p.x >> 17], 1);
    }
    __syncthreads();

    int v = (tid < 128) ? rcnt[tid] : 0;
    if (tid < 128) rcur[tid] = v;
    __syncthreads();
    for (int off = 1; off < 128; off <<= 1) {
        int t = 0;
        if (tid < 128 && tid >= off) t = rcur[tid - off];
        __syncthreads();
        if (tid < 128 && tid >= off) rcur[tid] += t;
        __syncthreads();
    }
    if (tid < 128) {
        int excl = rcur[tid] - v;
        rcur[tid] = excl;
        int row = b * 128 + tid;
        if (row < N_NODES) row_ptr[row] = s + excl;
    }
    __syncthreads();

    for (int j = tid; j < cnt; j += 512) {
        int2 p = se[j];
        int r = p.x >> 17;
        int pos = atomicAdd(&rcur[r], 1);
        part[s + pos] = make_int2(p.x & 0x1FFFF, p.y);
    }
}

// ---------------- weight split to MFMA-fragment-major layout (tiny, once) ----------------

__global__ __launch_bounds__(256)
void splitw_kernel(const float* __restrict__ w1, const float* __restrict__ w2,
                   unsigned short* __restrict__ w1f_hi, unsigned short* __restrict__ w1f_lo,
                   unsigned short* __restrict__ w2f_hi, unsigned short* __restrict__ w2f_lo) {
    const int W1_SLOTS = (IN_DIM / 32) * (HIDDEN / 16) * 64;   // 4096
    const int W2_SLOTS = (HIDDEN / 32) * (OUT_DIM / 16) * 64;  // 1024
    int g = blockIdx.x * 256 + threadIdx.x;
    if (g < W1_SLOTS) {
        int lane = g & 63;
        int rest = g >> 6;
        int nfrag = rest & 7;              // HIDDEN/16 = 8
        int kblk = rest >> 3;
        int n = nfrag * 16 + (lane & 15);
        int k0 = kblk * 32 + (lane >> 4) * 8;
#pragma unroll
        for (int j = 0; j < 8; j++) {
            unsigned short h, l;
            splitbf(w1[(size_t)(k0 + j) * HIDDEN + n], h, l);
            w1f_hi[(size_t)g * 8 + j] = h;
            w1f_lo[(size_t)g * 8 + j] = l;
        }
    } else if (g < W1_SLOTS + W2_SLOTS) {
        int g2 = g - W1_SLOTS;
        int lane = g2 & 63;
        int rest = g2 >> 6;
        int nfrag = rest & 3;              // OUT_DIM/16 = 4
        int kblk = rest >> 2;
        int n = nfrag * 16 + (lane & 15);
        int k0 = kblk * 32 + (lane >> 4) * 8;
#pragma unroll
        for (int j = 0; j < 8; j++) {
            unsigned short h, l;
            splitbf(w2[(size_t)(k0 + j) * OUT_DIM + n], h, l);
            w2f_hi[(size_t)g2 * 8 + j] = h;
            w2f_lo[(size_t)g2 * 8 + j] = l;
        }
    }
}

// ---------------- MFMA GEMM body (device fn): C(bf16) = A(fp32) @ B, split-bf16 3-product ----

template <int K, int BN>
__device__ __forceinline__ void gemm_body(int bx, char* smem, const float* __restrict__ A,
                                          const unsigned short* __restrict__ Bf_hi,
                                          const unsigned short* __restrict__ Bf_lo,
                                          ushort16* __restrict__ C, int M) {
    constexpr int BM = 128, BK = 64;
    constexpr int NF = BN / 32;
    unsigned short* Ah = (unsigned short*)smem;                 // 16384 B
    unsigned short* Al = (unsigned short*)(smem + BM * BK * 2); // 16384 B

    int tid = threadIdx.x;
    int wid = tid >> 6, lane = tid & 63;
    int wr = wid >> 1, wc = wid & 1;
    int rowBase = bx * BM;
    int r = lane & 15, kg = lane >> 4;
    int swzmask = (lane & 7) << 4;

    f32x4 zero = {0.f, 0.f, 0.f, 0.f};
    f32x4 acc[4][NF];
#pragma unroll
    for (int m = 0; m < 4; m++)
#pragma unroll
        for (int n = 0; n < NF; n++) acc[m][n] = zero;

    int sk4 = (tid & 15) * 4;
    int sm0 = tid >> 4;

    for (int k0 = 0; k0 < K; k0 += BK) {
#pragma unroll
        for (int i = 0; i < 8; i++) {
            int m = sm0 + i * 16;
            int row = rowBase + m;
            float4 f = make_float4(0.f, 0.f, 0.f, 0.f);
            if (row < M) f = *(const float4*)(A + (size_t)row * K + k0 + sk4);
            ushort4 h, l;
            splitbf(f.x, h.x, l.x);
            splitbf(f.y, h.y, l.y);
            splitbf(f.z, h.z, l.z);
            splitbf(f.w, h.w, l.w);
            int bo = (m * BK + sk4) * 2;
            int swz = bo ^ ((m & 7) << 4);
            *(ushort4*)((char*)Ah + swz) = h;
            *(ushort4*)((char*)Al + swz) = l;
        }
        __syncthreads();

#pragma unroll
        for (int kk = 0; kk < BK / 32; kk++) {
            short8 ah[4], al[4];
            int abase = (wr * 64 + r) * (BK * 2) + kk * 64 + kg * 16;
#pragma unroll
            for (int m = 0; m < 4; m++) {
                int swz = (abase + m * (16 * BK * 2)) ^ swzmask;
                ah[m] = *(const short8*)((const char*)Ah + swz);
                al[m] = *(const short8*)((const char*)Al + swz);
            }
            short8 bh[NF], bl[NF];
            int kblk = (k0 >> 5) + kk;
#pragma unroll
            for (int n = 0; n < NF; n++) {
                int nf = wc * NF + n;
                size_t off = ((size_t)(kblk * (BN / 16) + nf) * 64 + lane) * 8;
                bh[n] = *(const short8*)(Bf_hi + off);
                bl[n] = *(const short8*)(Bf_lo + off);
            }
#pragma unroll
            for (int m = 0; m < 4; m++)
#pragma unroll
                for (int n = 0; n < NF; n++) {
                    acc[m][n] = __builtin_amdgcn_mfma_f32_16x16x32_bf16(ah[m], bh[n], acc[m][n], 0, 0, 0);
                    acc[m][n] = __builtin_amdgcn_mfma_f32_16x16x32_bf16(ah[m], bl[n], acc[m][n], 0, 0, 0);
                    acc[m][n] = __builtin_amdgcn_mfma_f32_16x16x32_bf16(al[m], bh[n], acc[m][n], 0, 0, 0);
                }
        }
        __syncthreads();
    }

#pragma unroll
    for (int m = 0; m < 4; m++) {
        int row0 = rowBase + wr * 64 + m * 16 + kg * 4;
#pragma unroll
        for (int j = 0; j < 4; j++) {
            int row = row0 + j;
            if (row < M) {
#pragma unroll
                for (int n = 0; n < NF; n++) {
                    int col = wc * (BN / 2) + n * 16 + r;
                    C[(size_t)row * BN + col] = f2bf(acc[m][n][j]);
                }
            }
        }
    }
}

// standalone GEMM kernel (layer 2)
template <int K, int BN>
__launch_bounds__(256)
__global__ void gemm_mfma(const float* __restrict__ A,
                          const unsigned short* __restrict__ Bf_hi,
                          const unsigned short* __restrict__ Bf_lo,
                          ushort16* __restrict__ C, int M) {
    __shared__ __align__(16) char smem[32768];
    gemm_body<K, BN>(blockIdx.x, smem, A, Bf_hi, Bf_lo, C, M);
}

// ---------------- fused: pass-1 coarse partition (blocks < NPB) + gemm1 (blocks >= NPB) ----
// Deterministic placement via chunk_base: ZERO global atomics. Per-wave LDS histograms and
// cursors (4x less LDS atomic serialization). Output ordered by (group, chunk).

__launch_bounds__(256)
__global__ void partition_gemm1(const int* __restrict__ esrc, const int* __restrict__ edst,
                                const float* __restrict__ evals,
                                const int* __restrict__ chunk_base,
                                int2* __restrict__ part2, int E,
                                const float* __restrict__ A,
                                const unsigned short* __restrict__ w1f_hi,
                                const unsigned short* __restrict__ w1f_lo,
                                ushort16* __restrict__ pre1, int M) {
    __shared__ __align__(16) char smem[32768];
    if (blockIdx.x >= NPB) {
        gemm_body<IN_DIM, HIDDEN>(blockIdx.x - NPB, smem, A, w1f_hi, w1f_lo, pre1, M);
        return;
    }
    int2* sbp = (int2*)smem;                              // [0, 24576)
    unsigned char* sbg = (unsigned char*)(smem + 24576);  // [24576, 27648)
    int* whist = (int*)(smem + 27648);                    // [4 waves][16] counts->cursors
    int* tmp   = (int*)(smem + 27904);                    // 13 group totals
    int* lst   = (int*)(smem + 27968);                    // 13 chunk-local starts
    int* bpos  = (int*)(smem + 28032);                    // 13 global bases - lst

    int tid = threadIdx.x;
    int wid = tid >> 6;
    long base = (long)blockIdx.x * CHUNK;
    int cnt = (int)min((long)CHUNK, (long)E - base);

    if (tid < 64) whist[tid] = 0;
    __syncthreads();

    int d[NPT], sv[NPT]; float vv[NPT];
#pragma unroll
    for (int k = 0; k < NPT; k++) {
        int j = tid + k * 256;
        d[k] = -1;
        if (j < cnt) {
            d[k]  = edst[base + j];
            sv[k] = esrc[base + j];
            vv[k] = evals[base + j];
            atomicAdd(&whist[wid * 16 + (d[k] >> CGBITS)], 1);
        }
    }
    __syncthreads();

    if (tid < NCG)
        tmp[tid] = whist[tid] + whist[16 + tid] + whist[32 + tid] + whist[48 + tid];
    __syncthreads();
    if (tid == 0) {
        int run = 0;
#pragma unroll
        for (int g = 0; g < NCG; g++) { lst[g] = run; run += tmp[g]; }
    }
    __syncthreads();
    if (tid < NCG) {
        int g = tid;
        int c0 = whist[g], c1 = whist[16 + g], c2 = whist[32 + g];
        int l = lst[g];
        whist[g]      = l;
        whist[16 + g] = l + c0;
        whist[32 + g] = l + c0 + c1;
        whist[48 + g] = l + c0 + c1 + c2;
        bpos[g] = chunk_base[blockIdx.x * 16 + g] - l;
    }
    __syncthreads();

#pragma unroll
    for (int k = 0; k < NPT; k++) {
        if (d[k] >= 0) {
            int g = d[k] >> CGBITS;
            int pos = atomicAdd(&whist[wid * 16 + g], 1);
            sbg[pos] = (unsigned char)g;
            sbp[pos] = make_int2(sv[k] | ((d[k] & 8191) << 17), __float_as_int(vv[k]));
        }
    }
    __syncthreads();

    for (int j = tid; j < cnt; j += 256)
        part2[bpos[sbg[j]] + j] = sbp[j];
}

// ---------------- pass 2: coarse group -> 64 fine buckets ----------------

__global__ __launch_bounds__(256)
void pass2_kernel(const int2* __restrict__ part2, const int* __restrict__ bptr,
                  int* __restrict__ cursor, int2* __restrict__ part) {
    __shared__ __align__(16) int2 sbp[CHUNK];          // 24576
    __shared__ unsigned char sbb[CHUNK];               // 3072
    __shared__ int hist[64], lst[64], bpos[64];
    int tid = threadIdx.x;
    int g = blockIdx.x / MAXCH;
    int c = blockIdx.x % MAXCH;
    int gs = bptr[min(64 * g, NBUCK)];
    int ge = bptr[min(64 * (g + 1), NBUCK)];
    int base = gs + c * CHUNK;
    if (base >= ge) return;
    int cnt = min(CHUNK, ge - base);
    int b0 = g * 64;                                   // first fine bucket of group

    if (tid < 64) hist[tid] = 0;
    __syncthreads();

    int lb[NPT]; int2 pp[NPT];
#pragma unroll
    for (int k = 0; k < NPT; k++) {
        int j = tid + k * 256;
        lb[k] = -1;
        if (j < cnt) {
            pp[k] = part2[base + j];
            int dst = (g << CGBITS) | ((uint32)pp[k].x >> 17);
            lb[k] = (dst >> 7) - b0;                   // 0..63
            atomicAdd(&hist[lb[k]], 1);
        }
    }
    __syncthreads();

    if (tid < 64) {                                    // single-wave scan over 64 buckets
        int cc = hist[tid];
        int sum = cc;
#pragma unroll
        for (int off = 1; off < 64; off <<= 1) {
            int up = __shfl_up(sum, off);
            if (tid >= off) sum += up;
        }
        lst[tid] = sum - cc;
    }
    __syncthreads();

    if (tid < 64) {
        int cc = hist[tid];
        int gp = cc ? atomicAdd(&cursor[(b0 + tid) * CURSTRIDE], cc) : 0;
        bpos[tid] = gp - lst[tid];
        hist[tid] = lst[tid];
    }
    __syncthreads();

#pragma unroll
    for (int k = 0; k < NPT; k++) {
        int j = tid + k * 256;
        if (j < cnt) {
            int b = lb[k];
            int pos = atomicAdd(&hist[b], 1);
            sbb[pos] = (unsigned char)b;
            int dst = (g << CGBITS) | ((uint32)pp[k].x >> 17);
            sbp[pos] = make_int2((pp[k].x & 0x1FFFF) | ((dst & 127) << 17), pp[k].y);
        }
    }
    __syncthreads();

    for (int j = tid; j < cnt; j += 256)
        part[bpos[sbb[j]] + j] = sbp[j];
}

// ---------------- SpMM: wave per dst row, multi-edge-per-gather, deep pipeline ----------------

template <int D, bool RELU>
__launch_bounds__(256)
__global__ void spmm_kernel(const ushort16* __restrict__ feat, const int2* __restrict__ csr_pair,
                            const int* __restrict__ row_ptr, float* __restrict__ out, int n) {
    constexpr int LPR = D * 2 / 16;      // lanes per row: 16 (D=128) or 8 (D=64)
    constexpr int EPG = 64 / LPR;        // edges per gather: 4 or 8
    constexpr int DEPTH = (D == 128) ? 8 : 4;
    int wid = threadIdx.x >> 6;
    int lane = threadIdx.x & 63;
    int row = blockIdx.x * 4 + wid;
    if (row >= n) return;
    int s = row_ptr[row], e = row_ptr[row + 1];

    int sub = lane / LPR;
    int slot = lane % LPR;
    const char* fbase = (const char*)feat + slot * 16;

    float acc[8];
#pragma unroll
    for (int j = 0; j < 8; j++) acc[j] = 0.f;

    for (int i = s; i < e; i += DEPTH * EPG) {
        int2 p[DEPTH]; float v[DEPTH]; uint4 u[DEPTH];
#pragma unroll
        for (int q = 0; q < DEPTH; q++) {
            int ii = i + q * EPG + sub;
            p[q] = csr_pair[min(ii, e - 1)];
            v[q] = (ii < e) ? __int_as_float(p[q].y) : 0.f;
        }
#pragma unroll
        for (int q = 0; q < DEPTH; q++)
            u[q] = *(const uint4*)(fbase + (size_t)p[q].x * (D * 2));
#pragma unroll
        for (int q = 0; q < DEPTH; q++) {
#pragma unroll
            for (int t = 0; t < 4; t++) {
                uint32 w = (&u[q].x)[t];
                acc[2 * t]     += v[q] * __uint_as_float(w << 16);
                acc[2 * t + 1] += v[q] * __uint_as_float(w & 0xffff0000u);
            }
        }
    }

#pragma unroll
    for (int m = LPR; m < 64; m <<= 1) {
#pragma unroll
        for (int j = 0; j < 8; j++) acc[j] += __shfl_xor(acc[j], m);
    }

    if (RELU) {
#pragma unroll
        for (int j = 0; j < 8; j++) acc[j] = acc[j] > 0.f ? acc[j] : 0.f;
    }

    if (lane < LPR) {
        float4* o = (float4*)(out + (size_t)row * D + slot * 8);
        o[0] = make_float4(acc[0], acc[1], acc[2], acc[3]);
        o[1] = make_float4(acc[4], acc[5], acc[6], acc[7]);
    }
}

// ---------------- launch ----------------

extern "C" void kernel_launch(void* const* d_in, const int* in_sizes, int n_in,
                              void* d_out, int out_size, void* d_ws, size_t ws_size,
                              hipStream_t stream) {
    const float* x    = (const float*)d_in[0];
    const float* adj  = (const float*)d_in[1];
    const float* w1   = (const float*)d_in[2];
    const float* w2   = (const float*)d_in[3];
    const int*   esrc = (const int*)d_in[4];
    const int*   edst = (const int*)d_in[5];
    float* out = (float*)d_out;

    const int N = N_NODES;
    const int E = N_EDGES;

    char* ws = (char*)d_ws;
    size_t off = 0;
    auto take = [&](size_t bytes) -> char* {
        char* p = ws + off;
        off = (off + bytes + 255) & ~(size_t)255;
        return p;
    };
    int*      bcnt       = (int*)take((size_t)NBUCK * 4);
    int*      bptr       = (int*)take((size_t)(NBUCK + 1) * 4);
    int*      cursor     = (int*)take((size_t)NBUCK * CURSTRIDE * 4);  // fine-bucket cursors
    int*      chunk_hist = (int*)take((size_t)NPB * 16 * 4);           // per-chunk group counts
    int*      chunk_base = (int*)take((size_t)NPB * 16 * 4);           // deterministic bases
    int*      row_ptr    = (int*)take((size_t)(N + 1) * 4);
    int2*     part       = (int2*)take((size_t)E * 8);        // becomes row-sorted CSR
    int2*     part2      = (int2*)take((size_t)E * 8);        // coarse-grouped temp
    ushort16* pre1       = (ushort16*)take((size_t)N * HIDDEN * 2);    // bf16
    ushort16* pre2       = (ushort16*)take((size_t)N * OUT_DIM * 2);   // bf16
    float*    h          = (float*)take((size_t)N * HIDDEN * 4);       // fp32
    unsigned short* w1f_hi = (unsigned short*)take((size_t)HIDDEN * IN_DIM * 2);
    unsigned short* w1f_lo = (unsigned short*)take((size_t)HIDDEN * IN_DIM * 2);
    unsigned short* w2f_hi = (unsigned short*)take((size_t)OUT_DIM * HIDDEN * 2);
    unsigned short* w2f_lo = (unsigned short*)take((size_t)OUT_DIM * HIDDEN * 2);

    // weight split to fragment-major (tiny)
    splitw_kernel<<<20, 256, 0, stream>>>(w1, w2, w1f_hi, w1f_lo, w2f_hi, w2f_lo);

    // CSR build prologue
    hipMemsetAsync(bcnt, 0, (size_t)NBUCK * 4, stream);
    hist_bucket<<<NPB, 256, 0, stream>>>(edst, bcnt, chunk_hist, E);
    bucket_scan<<<1, 256, 0, stream>>>(bcnt, bptr, cursor, row_ptr, E);
    scan_chunks<<<NCG, 256, 0, stream>>>(chunk_hist, bptr, chunk_base);

    // Fused: pass-1 coarse partition (atomic-free placement) + gemm1 pre1 = bf16(X@W1)
    partition_gemm1<<<NPB + (N_NODES + 127) / 128, 256, 0, stream>>>(
        esrc, edst, adj, chunk_base, part2, E, x, w1f_hi, w1f_lo, pre1, N);

    // pass 2: coarse groups -> fine buckets
    pass2_kernel<<<NCG * MAXCH, 256, 0, stream>>>(part2, bptr, cursor, part);

    bucket_to_csr<<<NBUCK, 512, 0, stream>>>(bptr, part, row_ptr);

    // Layer 1 SpMM: h = relu(A @ pre1) in fp32
    spmm_kernel<HIDDEN, true><<<(N + 3) / 4, 256, 0, stream>>>(pre1, part, row_ptr, h, N);

    // Layer 2: pre2 = bf16(h@W2) via MFMA ; out = A @ pre2 in fp32
    gemm_mfma<HIDDEN, OUT_DIM><<<(N + 127) / 128, 256, 0, stream>>>(h, w2f_hi, w2f_lo, pre2, N);
    spmm_kernel<OUT_DIM, false><<<(N + 3) / 4, 256, 0, stream>>>(pre2, part, row_ptr, out, N);
}